// Round 18
// baseline (180.193 us; speedup 1.0000x reference)
//
#include <hip/hip_runtime.h>

#define Lq 512
#define Bn 1024
#define Tq 48

typedef float f32x4 __attribute__((ext_vector_type(4)));
typedef short s16x8 __attribute__((ext_vector_type(8)));
typedef unsigned u32x4 __attribute__((ext_vector_type(4)));

#define MFMA(a, b, c) __builtin_amdgcn_mfma_f32_16x16x32_bf16((a), (b), (c), 0, 0, 0)
#define SB __builtin_amdgcn_sched_barrier(0)

__device__ __forceinline__ unsigned cvtpk(float lo, float hi) {
    unsigned r;
    asm("v_cvt_pk_bf16_f32 %0, %1, %2" : "=v"(r) : "v"(lo), "v"(hi));
    return r;
}
__device__ __forceinline__ short f2b(float x) {       // fp32 -> bf16 bits, RNE
    unsigned u = __float_as_uint(x);
    return (short)((u + 0x7fffu + ((u >> 16) & 1u)) >> 16);
}

// rebuild B fragments from this lane's own pn [R11-proven]
#define PACKB do {                                                            \
    unsigned d0_ = cvtpk(pn0[0], pn0[1]), d1_ = cvtpk(pn0[2], pn0[3]);        \
    unsigned d2_ = cvtpk(pn1[0], pn1[1]), d3_ = cvtpk(pn1[2], pn1[3]);        \
    unsigned d4_ = cvtpk(pn2[0], pn2[1]), d5_ = cvtpk(pn2[2], pn2[3]);        \
    u32x4 b0_ = {d0_, d1_, d2_, d3_};                                         \
    u32x4 b1_ = {d4_, d5_, 0u, 0u};                                           \
    Bk0 = __builtin_bit_cast(s16x8, b0_);                                     \
    Bk1 = __builtin_bit_cast(s16x8, b1_);                                     \
} while (0)

// one forward step [R11/R14-proven]
#define STEP(EA, EB, EC, MV, RS) do {                                         \
    f32x4 C0_ = MFMA(aw00, Bk0, Zf); C0_ = MFMA(aw01, Bk1, C0_);              \
    f32x4 C1_ = MFMA(aw10, Bk0, Zf); C1_ = MFMA(aw11, Bk1, C1_);              \
    f32x4 C2_ = MFMA(aw20, Bk0, Zf); C2_ = MFMA(aw21, Bk1, C2_);              \
    pn0[0] = (MV) ? C0_[0] * __expf((EA)[0]) : pn0[0];                        \
    pn0[1] = (MV) ? C0_[1] * __expf((EA)[1]) : pn0[1];                        \
    pn0[2] = (MV) ? C0_[2] * __expf((EA)[2]) : pn0[2];                        \
    pn0[3] = (MV) ? C0_[3] * __expf((EA)[3]) : pn0[3];                        \
    pn1[0] = (MV) ? C1_[0] * __expf((EB)[0]) : pn1[0];                        \
    pn1[1] = (MV) ? C1_[1] * __expf((EB)[1]) : pn1[1];                        \
    pn1[2] = (MV) ? C1_[2] * __expf((EB)[2]) : pn1[2];                        \
    pn1[3] = (MV) ? C1_[3] * __expf((EB)[3]) : pn1[3];                        \
    pn2[0] = (MV) ? C2_[0] * __expf((EC)[0]) : pn2[0];                        \
    pn2[1] = (MV) ? C2_[1] * __expf((EC)[1]) : pn2[1];                        \
    pn2[2] = (MV) ? C2_[2] * __expf((EC)[2]) : pn2[2];                        \
    pn2[3] = (MV) ? C2_[3] * __expf((EC)[3]) : pn2[3];                        \
    if (RS) {                                                                 \
        float rep_ = __shfl(pn0[0], cidx, 64);                                \
        int k_ = ((__float_as_int(rep_) >> 23) & 0xff) - 126;                 \
        float scl_ = __int_as_float((127 - k_) << 23);                        \
        pn0[0]*=scl_; pn0[1]*=scl_; pn0[2]*=scl_; pn0[3]*=scl_;               \
        pn1[0]*=scl_; pn1[1]*=scl_; pn1[2]*=scl_; pn1[3]*=scl_;               \
        pn2[0]*=scl_; pn2[1]*=scl_; pn2[2]*=scl_; pn2[3]*=scl_;               \
        c2 += k_;                                                             \
    }                                                                         \
    PACKB;                                                                    \
} while (0)

// plain-C slot refill (R14 main kernel)
#define LOAD_SLOT(D, T) do {                                                  \
    int t_ = (T); int v_ = (t_ < Lq); int tc_ = v_ ? t_ : (Lq - 1);           \
    const float* ep_ = em + ((size_t)tc_ * Bn + bidx) * Tq;                   \
    ea_##D = *(const f32x4*)(ep_ + 4 * qidx);                                 \
    eb_##D = *(const f32x4*)(ep_ + 16 + 4 * qidx);                            \
    ec_##D = *(const f32x4*)(ep_ + 32 + 4 * qidx);                            \
    m_##D  = v_ ? mask[tc_ * Bn + bidx] : 0;                                  \
} while (0)

// asm slot refill (diag_mem; R16-proven to compile/run correctly)
#define LOAD_SLOT_ASM(D, T) do {                                              \
    int t_ = (T);                                                             \
    const float* ep_ = em + ((size_t)t_ * Bn + bidx) * Tq + 4 * qidx;         \
    const int*   mp_ = mask + t_ * Bn + bidx;                                 \
    asm volatile("global_load_dwordx4 %0, %1, off" : "=v"(ea_##D) : "v"(ep_));      \
    asm volatile("global_load_dwordx4 %0, %1, off" : "=v"(eb_##D) : "v"(ep_ + 16)); \
    asm volatile("global_load_dwordx4 %0, %1, off" : "=v"(ec_##D) : "v"(ep_ + 32)); \
    asm volatile("global_load_dword %0, %1, off"   : "=v"(mv_##D) : "v"(mp_));      \
} while (0)

#define WAITP do { asm volatile("s_waitcnt vmcnt(12)"); SB; } while (0)

// A-fragment build from staged trans (shared by main + diag_chain)
#define BUILD_AW do {                                                         \
    _Pragma("unroll")                                                         \
    for (int i = 0; i < 8; ++i) {                                             \
        int l0 = (i < 4) ? (4 * qidx + i) : (12 + 4 * qidx + i);              \
        aw00[i] = f2b(__expf(shf[l0 * Tq + cidx]));                           \
        aw10[i] = f2b(__expf(shf[l0 * Tq + 16 + cidx]));                      \
        aw20[i] = f2b(__expf(shf[l0 * Tq + 32 + cidx]));                      \
        if (i < 4) {                                                          \
            int l1 = 32 + 4 * qidx + i;                                       \
            aw01[i] = f2b(__expf(shf[l1 * Tq + cidx]));                       \
            aw11[i] = f2b(__expf(shf[l1 * Tq + 16 + cidx]));                  \
            aw21[i] = f2b(__expf(shf[l1 * Tq + 32 + cidx]));                  \
        } else {                                                              \
            aw01[i] = 0; aw11[i] = 0; aw21[i] = 0;                            \
        }                                                                     \
    }                                                                         \
} while (0)

// ---------------- Main fused kernel (R14 verbatim, last-known-best) --------
__global__ __launch_bounds__(64, 1) void crf_fused(
    const float* __restrict__ em, const int* __restrict__ tags,
    const int* __restrict__ mask, const float* __restrict__ startT,
    const float* __restrict__ endT, const float* __restrict__ trans,
    float* __restrict__ out)
{
    const int j = threadIdx.x;
    __shared__ float shf[Tq * Tq];

    if (blockIdx.x < 64) {
        const int cidx = j & 15;
        const int qidx = j >> 4;
        const int bidx = blockIdx.x * 16 + cidx;

        for (int i = j; i < Tq * Tq; i += 64) shf[i] = trans[i];
        __syncthreads();
        s16x8 aw00, aw01, aw10, aw11, aw20, aw21;
        BUILD_AW;

        f32x4 pn0, pn1, pn2;
        {
            const float* e0p = em + (size_t)bidx * Tq;
            f32x4 ea = *(const f32x4*)(e0p + 4 * qidx);
            f32x4 eb = *(const f32x4*)(e0p + 16 + 4 * qidx);
            f32x4 ec = *(const f32x4*)(e0p + 32 + 4 * qidx);
#pragma unroll
            for (int i = 0; i < 4; ++i) {
                pn0[i] = __expf(startT[ 0 + 4 * qidx + i] + ea[i]);
                pn1[i] = __expf(startT[16 + 4 * qidx + i] + eb[i]);
                pn2[i] = __expf(startT[32 + 4 * qidx + i] + ec[i]);
            }
        }

        const f32x4 Zf = {0.f, 0.f, 0.f, 0.f};
        s16x8 Bk0, Bk1;
        int c2 = 0;
        PACKB;

        f32x4 ea_0, eb_0, ec_0, ea_1, eb_1, ec_1;
        f32x4 ea_2, eb_2, ec_2, ea_3, eb_3, ec_3;
        int m_0, m_1, m_2, m_3;
        LOAD_SLOT(0, 1); LOAD_SLOT(1, 2); LOAD_SLOT(2, 3); LOAD_SLOT(3, 4);

        for (int ch = 0; ch < 128; ++ch) {
            const int tb = 1 + 4 * ch;
            STEP(ea_0, eb_0, ec_0, m_0, 0); LOAD_SLOT(0, tb + 4);
            STEP(ea_1, eb_1, ec_1, m_1, 0); LOAD_SLOT(1, tb + 5);
            STEP(ea_2, eb_2, ec_2, m_2, 0); LOAD_SLOT(2, tb + 6);
            STEP(ea_3, eb_3, ec_3, m_3, 1); LOAD_SLOT(3, tb + 7);
        }

        float zacc = 0.f;
#pragma unroll
        for (int i = 0; i < 4; ++i) {
            zacc += pn0[i] * __expf(endT[ 0 + 4 * qidx + i]);
            zacc += pn1[i] * __expf(endT[16 + 4 * qidx + i]);
            zacc += pn2[i] * __expf(endT[32 + 4 * qidx + i]);
        }
        zacc += __shfl_xor(zacc, 16, 64);
        zacc += __shfl_xor(zacc, 32, 64);
        float nl = -(__logf(zacc) + (float)c2 * 0.6931471805599453f);
        nl += __shfl_xor(nl, 1, 64);
        nl += __shfl_xor(nl, 2, 64);
        nl += __shfl_xor(nl, 4, 64);
        nl += __shfl_xor(nl, 8, 64);
        if (j == 0) atomicAdd(out, nl);
    } else {
        const int bid = blockIdx.x - 64;
        float c = 0.0f;
        for (int id = bid * 64 + j; id < Lq * Bn; id += 512 * 64) {
            int t  = id >> 10;
            int bb = id & (Bn - 1);
            int tag = tags[id];
            int m_t = mask[id];
            if (t == 0) c += startT[tag];
            bool is_last;
            if (t < Lq - 1) {
                if (m_t) c += em[(size_t)id * Tq + tag];
                int tag1 = tags[id + Bn];
                int m1   = mask[id + Bn];
                if (m1) c += trans[tag * Tq + tag1];
                is_last = (m_t != 0) && (m1 == 0);
            } else {
                is_last = (m_t != 0);
            }
            if (is_last) {
                c += endT[tag];
                int mL = mask[(Lq - 1) * Bn + bb];
                if (mL) c += em[((size_t)(Lq - 1) * Bn + bb) * Tq + tag];
            }
        }
#pragma unroll
        for (int off = 32; off >= 1; off >>= 1)
            c += __shfl_xor(c, off, 64);
        if (j == 0) atomicAdd(out, c);
    }
}

// ---------------- DIAG B: chain-only (no in-loop memory), 128 steps --------
// Identical STEP structure; emissions synthesized from loop counter so the
// 12 exps/step cannot be hoisted; mask loaded once (runtime). Writes to ws.
__global__ __launch_bounds__(64, 1) void diag_chain(
    const float* __restrict__ em, const int* __restrict__ mask,
    const float* __restrict__ startT, const float* __restrict__ trans,
    float* __restrict__ ws)
{
    const int j = threadIdx.x;
    const int cidx = j & 15;
    const int qidx = j >> 4;
    const int bidx = blockIdx.x * 16 + cidx;
    __shared__ float shf[Tq * Tq];

    for (int i = j; i < Tq * Tq; i += 64) shf[i] = trans[i];
    __syncthreads();
    s16x8 aw00, aw01, aw10, aw11, aw20, aw21;
    BUILD_AW;

    f32x4 pn0, pn1, pn2;
    {
        const float* e0p = em + (size_t)bidx * Tq;
        f32x4 ea = *(const f32x4*)(e0p + 4 * qidx);
        f32x4 eb = *(const f32x4*)(e0p + 16 + 4 * qidx);
        f32x4 ec = *(const f32x4*)(e0p + 32 + 4 * qidx);
#pragma unroll
        for (int i = 0; i < 4; ++i) {
            pn0[i] = __expf(startT[ 0 + 4 * qidx + i] + ea[i]);
            pn1[i] = __expf(startT[16 + 4 * qidx + i] + eb[i]);
            pn2[i] = __expf(startT[32 + 4 * qidx + i] + ec[i]);
        }
    }

    const f32x4 Zf = {0.f, 0.f, 0.f, 0.f};
    s16x8 Bk0, Bk1;
    int c2 = 0;
    PACKB;

    const int mc = mask[bidx];                 // runtime 1
    const f32x4 o0 = {0.11f, 0.23f, 0.31f, 0.47f};
    const f32x4 o1 = {0.13f, 0.29f, 0.37f, 0.41f};
    const f32x4 o2 = {0.17f, 0.19f, 0.43f, 0.53f};

    for (int ch = 0; ch < 32; ++ch) {          // 128 steps
        float fb = (float)ch * 0.001f;
        f32x4 eA0 = o0 + fb, eB0 = o1 + fb, eC0 = o2 + fb;
        f32x4 eA1 = o0 + (fb + 0.01f), eB1 = o1 + (fb + 0.01f), eC1 = o2 + (fb + 0.01f);
        f32x4 eA2 = o0 + (fb + 0.02f), eB2 = o1 + (fb + 0.02f), eC2 = o2 + (fb + 0.02f);
        f32x4 eA3 = o0 + (fb + 0.03f), eB3 = o1 + (fb + 0.03f), eC3 = o2 + (fb + 0.03f);
        STEP(eA0, eB0, eC0, mc, 0);
        STEP(eA1, eB1, eC1, mc, 0);
        STEP(eA2, eB2, eC2, mc, 0);
        STEP(eA3, eB3, eC3, mc, 1);
    }

    float s = pn0[0]+pn0[1]+pn0[2]+pn0[3] + pn1[0]+pn1[1]+pn1[2]+pn1[3]
            + pn2[0]+pn2[1]+pn2[2]+pn2[3] + (float)c2;
#pragma unroll
    for (int off = 32; off >= 1; off >>= 1) s += __shfl_xor(s, off, 64);
    if (j == 0) ws[64 + blockIdx.x] = s;
}

// ---------------- DIAG C: memory-only (no compute), 128 steps --------------
// Identical asm-load + counted-vmcnt stream; consumption is 12 f32 adds.
__global__ __launch_bounds__(64, 1) void diag_mem(
    const float* __restrict__ em, const int* __restrict__ mask,
    float* __restrict__ ws)
{
    const int j = threadIdx.x;
    const int qidx = j >> 4;
    const int bidx = blockIdx.x * 16 + (j & 15);

    f32x4 ea_0, eb_0, ec_0, ea_1, eb_1, ec_1;
    f32x4 ea_2, eb_2, ec_2, ea_3, eb_3, ec_3;
    int mv_0, mv_1, mv_2, mv_3;

    asm volatile("s_waitcnt vmcnt(0)");
    LOAD_SLOT_ASM(0, 1); LOAD_SLOT_ASM(1, 2); LOAD_SLOT_ASM(2, 3); LOAD_SLOT_ASM(3, 4);

    f32x4 a0 = {0,0,0,0}, a1 = {0,0,0,0}, a2 = {0,0,0,0};
    int ms = 0;
    for (int ch = 0; ch < 32; ++ch) {          // 128 steps
        const int tb = 1 + 4 * ch;
        WAITP; a0 += ea_0; a1 += eb_0; a2 += ec_0; ms += mv_0; LOAD_SLOT_ASM(0, tb + 4);
        WAITP; a0 += ea_1; a1 += eb_1; a2 += ec_1; ms += mv_1; LOAD_SLOT_ASM(1, tb + 5);
        WAITP; a0 += ea_2; a1 += eb_2; a2 += ec_2; ms += mv_2; LOAD_SLOT_ASM(2, tb + 6);
        WAITP; a0 += ea_3; a1 += eb_3; a2 += ec_3; ms += mv_3; LOAD_SLOT_ASM(3, tb + 7);
    }
    asm volatile("s_waitcnt vmcnt(0)");

    float s = a0[0]+a0[1]+a0[2]+a0[3] + a1[0]+a1[1]+a1[2]+a1[3]
            + a2[0]+a2[1]+a2[2]+a2[3] + (float)ms;
#pragma unroll
    for (int off = 32; off >= 1; off >>= 1) s += __shfl_xor(s, off, 64);
    if (j == 0) ws[128 + blockIdx.x] = s;
}

extern "C" void kernel_launch(void* const* d_in, const int* in_sizes, int n_in,
                              void* d_out, int out_size, void* d_ws, size_t ws_size,
                              hipStream_t stream) {
    const float* em     = (const float*)d_in[0];
    const int*   tags   = (const int*)d_in[1];
    const int*   mask   = (const int*)d_in[2];
    const float* startT = (const float*)d_in[3];
    const float* endT   = (const float*)d_in[4];
    const float* trans  = (const float*)d_in[5];
    float* out = (float*)d_out;
    float* ws  = (float*)d_ws;

    hipMemsetAsync(out, 0, sizeof(float), stream);
    crf_fused<<<576, 64, 0, stream>>>(em, tags, mask, startT, endT, trans, out);
    if (ws_size >= 4096) {
        diag_chain<<<64, 64, 0, stream>>>(em, mask, startT, trans, ws);
        diag_mem<<<64, 64, 0, stream>>>(em, mask, ws);
    }
}

// Round 19
// 129.645 us; speedup vs baseline: 1.3899x; 1.3899x over previous
//
#include <hip/hip_runtime.h>

#define Lq 512
#define Bn 1024
#define Tq 48

typedef float f32x4 __attribute__((ext_vector_type(4)));
typedef short s16x8 __attribute__((ext_vector_type(8)));
typedef unsigned u32x4 __attribute__((ext_vector_type(4)));

#define MFMA(a, b, c) __builtin_amdgcn_mfma_f32_16x16x32_bf16((a), (b), (c), 0, 0, 0)
#define SB __builtin_amdgcn_sched_barrier(0)

__device__ __forceinline__ unsigned cvtpk(float lo, float hi) {
    unsigned r;
    asm("v_cvt_pk_bf16_f32 %0, %1, %2" : "=v"(r) : "v"(lo), "v"(hi));
    return r;
}
__device__ __forceinline__ short f2b(float x) {       // fp32 -> bf16 bits, RNE
    unsigned u = __float_as_uint(x);
    return (short)((u + 0x7fffu + ((u >> 16) & 1u)) >> 16);
}

// rebuild B fragments from this lane's own pn [R11-proven]
#define PACKB do {                                                            \
    unsigned d0_ = cvtpk(pn0[0], pn0[1]), d1_ = cvtpk(pn0[2], pn0[3]);        \
    unsigned d2_ = cvtpk(pn1[0], pn1[1]), d3_ = cvtpk(pn1[2], pn1[3]);        \
    unsigned d4_ = cvtpk(pn2[0], pn2[1]), d5_ = cvtpk(pn2[2], pn2[3]);        \
    u32x4 b0_ = {d0_, d1_, d2_, d3_};                                         \
    u32x4 b1_ = {d4_, d5_, 0u, 0u};                                           \
    Bk0 = __builtin_bit_cast(s16x8, b0_);                                     \
    Bk1 = __builtin_bit_cast(s16x8, b1_);                                     \
} while (0)

// one forward step. R19: EA/EB/EC are PRE-EXPONENTIATED (exp moved off the
// recurrence chain into a pipeline stage); rescale uses scl_/k_ precomputed
// one step earlier (shfl latency overlapped). Chain = MFMA->mul->sel->cvtpk.
#define STEP(EA, EB, EC, MV, RS) do {                                         \
    f32x4 C0_ = MFMA(aw00, Bk0, Zf); C0_ = MFMA(aw01, Bk1, C0_);              \
    f32x4 C1_ = MFMA(aw10, Bk0, Zf); C1_ = MFMA(aw11, Bk1, C1_);              \
    f32x4 C2_ = MFMA(aw20, Bk0, Zf); C2_ = MFMA(aw21, Bk1, C2_);              \
    pn0[0] = (MV) ? C0_[0] * (EA)[0] : pn0[0];                                \
    pn0[1] = (MV) ? C0_[1] * (EA)[1] : pn0[1];                                \
    pn0[2] = (MV) ? C0_[2] * (EA)[2] : pn0[2];                                \
    pn0[3] = (MV) ? C0_[3] * (EA)[3] : pn0[3];                                \
    pn1[0] = (MV) ? C1_[0] * (EB)[0] : pn1[0];                                \
    pn1[1] = (MV) ? C1_[1] * (EB)[1] : pn1[1];                                \
    pn1[2] = (MV) ? C1_[2] * (EB)[2] : pn1[2];                                \
    pn1[3] = (MV) ? C1_[3] * (EB)[3] : pn1[3];                                \
    pn2[0] = (MV) ? C2_[0] * (EC)[0] : pn2[0];                                \
    pn2[1] = (MV) ? C2_[1] * (EC)[1] : pn2[1];                                \
    pn2[2] = (MV) ? C2_[2] * (EC)[2] : pn2[2];                                \
    pn2[3] = (MV) ? C2_[3] * (EC)[3] : pn2[3];                                \
    if (RS) {                                                                 \
        pn0[0]*=scl_; pn0[1]*=scl_; pn0[2]*=scl_; pn0[3]*=scl_;               \
        pn1[0]*=scl_; pn1[1]*=scl_; pn1[2]*=scl_; pn1[3]*=scl_;               \
        pn2[0]*=scl_; pn2[1]*=scl_; pn2[2]*=scl_; pn2[3]*=scl_;               \
        c2 += k_;                                                             \
    }                                                                         \
    PACKB;                                                                    \
} while (0)

// read the column-representative exponent (1 step BEFORE application; the
// ds_bpermute latency overlaps STEP(3)). Exact power-of-2 accounting.
#define KREAD do {                                                            \
    float rep_ = __shfl(pn0[0], cidx, 64);                                    \
    k_ = ((__float_as_int(rep_) >> 23) & 0xff) - 126;                         \
    scl_ = __int_as_float((127 - k_) << 23);                                  \
} while (0)

// refill slot D (RAW e + mask) via asm loads: issue pinned here [R16-proven]
#define LOAD_SLOT(D, T) do {                                                  \
    int t_ = (T); vf_##D = (t_ < Lq); int tc_ = vf_##D ? t_ : (Lq - 1);       \
    const float* ep_ = em + ((size_t)tc_ * Bn + bidx) * Tq + 4 * qidx;        \
    const int*   mp_ = mask + tc_ * Bn + bidx;                                \
    asm volatile("global_load_dwordx4 %0, %1, off" : "=v"(ea_##D) : "v"(ep_));      \
    asm volatile("global_load_dwordx4 %0, %1, off" : "=v"(eb_##D) : "v"(ep_ + 16)); \
    asm volatile("global_load_dwordx4 %0, %1, off" : "=v"(ec_##D) : "v"(ep_ + 32)); \
    asm volatile("global_load_dword %0, %1, off"   : "=v"(mv_##D) : "v"(mp_));      \
} while (0)

// wait until the OLDEST slot's 4 loads are done (12 younger stay in flight)
#define WAITP do { asm volatile("s_waitcnt vmcnt(12)"); SB; } while (0)

// exponentiate slot D in place (its loads were completed by WAITP; its
// consuming STEP is 1 step away -> exp runs in the slack, off the chain)
#define EXP_SLOT(D) do {                                                      \
    ea_##D[0]=__expf(ea_##D[0]); ea_##D[1]=__expf(ea_##D[1]);                 \
    ea_##D[2]=__expf(ea_##D[2]); ea_##D[3]=__expf(ea_##D[3]);                 \
    eb_##D[0]=__expf(eb_##D[0]); eb_##D[1]=__expf(eb_##D[1]);                 \
    eb_##D[2]=__expf(eb_##D[2]); eb_##D[3]=__expf(eb_##D[3]);                 \
    ec_##D[0]=__expf(ec_##D[0]); ec_##D[1]=__expf(ec_##D[1]);                 \
    ec_##D[2]=__expf(ec_##D[2]); ec_##D[3]=__expf(ec_##D[3]);                 \
} while (0)

// ---------------- Fused kernel ----------------
// blocks 0..63: MFMA forward algorithm (16 batch columns per wave).
// blocks 64..575: numerator (gold-path score), grid-stride.
__global__ __launch_bounds__(64, 1) void crf_fused(
    const float* __restrict__ em, const int* __restrict__ tags,
    const int* __restrict__ mask, const float* __restrict__ startT,
    const float* __restrict__ endT, const float* __restrict__ trans,
    float* __restrict__ out)
{
    const int j = threadIdx.x;
    __shared__ float shf[Tq * Tq];

    if (blockIdx.x < 64) {
        // ---------------- forward path ----------------
        const int cidx = j & 15;          // batch column within wave
        const int qidx = j >> 4;          // k-slot group
        const int bidx = blockIdx.x * 16 + cidx;

        // stage trans, then build W^T A-fragments under the kappa-slot
        // permutation PACKB uses [R11-proven]
        for (int i = j; i < Tq * Tq; i += 64) shf[i] = trans[i];
        __syncthreads();
        s16x8 aw00, aw01, aw10, aw11, aw20, aw21;
#pragma unroll
        for (int i = 0; i < 8; ++i) {
            int l0 = (i < 4) ? (4 * qidx + i) : (12 + 4 * qidx + i);
            aw00[i] = f2b(__expf(shf[l0 * Tq + cidx]));
            aw10[i] = f2b(__expf(shf[l0 * Tq + 16 + cidx]));
            aw20[i] = f2b(__expf(shf[l0 * Tq + 32 + cidx]));
            if (i < 4) {
                int l1 = 32 + 4 * qidx + i;
                aw01[i] = f2b(__expf(shf[l1 * Tq + cidx]));
                aw11[i] = f2b(__expf(shf[l1 * Tq + 16 + cidx]));
                aw21[i] = f2b(__expf(shf[l1 * Tq + 32 + cidx]));
            } else {
                aw01[i] = 0; aw11[i] = 0; aw21[i] = 0;
            }
        }

        // P_0 (C layout): pn_n[i] = exp(start[s]+em0[s]), s = 16n+4q+i
        f32x4 pn0, pn1, pn2;
        {
            const float* e0p = em + (size_t)bidx * Tq;
            f32x4 ea = *(const f32x4*)(e0p + 4 * qidx);
            f32x4 eb = *(const f32x4*)(e0p + 16 + 4 * qidx);
            f32x4 ec = *(const f32x4*)(e0p + 32 + 4 * qidx);
#pragma unroll
            for (int i = 0; i < 4; ++i) {
                pn0[i] = __expf(startT[ 0 + 4 * qidx + i] + ea[i]);
                pn1[i] = __expf(startT[16 + 4 * qidx + i] + eb[i]);
                pn2[i] = __expf(startT[32 + 4 * qidx + i] + ec[i]);
            }
        }

        const f32x4 Zf = {0.f, 0.f, 0.f, 0.f};
        s16x8 Bk0, Bk1;
        int c2 = 0;
        int k_ = 0; float scl_ = 1.0f;
        PACKB;

        // 4 prefetch slots in asm-pinned registers (raw -> exp'd in place)
        f32x4 ea_0, eb_0, ec_0, ea_1, eb_1, ec_1;
        f32x4 ea_2, eb_2, ec_2, ea_3, eb_3, ec_3;
        int mv_0, mv_1, mv_2, mv_3;
        int vf_0, vf_1, vf_2, vf_3;

        // prologue: zero vmcnt baseline, fill 4 slots, exp slot 0
        asm volatile("s_waitcnt vmcnt(0)");
        LOAD_SLOT(0, 1); LOAD_SLOT(1, 2); LOAD_SLOT(2, 3); LOAD_SLOT(3, 4);
        WAITP;            // slot 0's loads complete
        EXP_SLOT(0);

        // 128 chunks x 4 steps; rescale applied at pos 3 with k read at pos 2
        for (int ch = 0; ch < 128; ++ch) {
            const int tb = 1 + 4 * ch;
            STEP(ea_0, eb_0, ec_0, (mv_0 & vf_0), 0);
            LOAD_SLOT(0, tb + 4); WAITP; EXP_SLOT(1);
            STEP(ea_1, eb_1, ec_1, (mv_1 & vf_1), 0);
            LOAD_SLOT(1, tb + 5); WAITP; EXP_SLOT(2);
            STEP(ea_2, eb_2, ec_2, (mv_2 & vf_2), 0); KREAD;
            LOAD_SLOT(2, tb + 6); WAITP; EXP_SLOT(3);
            STEP(ea_3, eb_3, ec_3, (mv_3 & vf_3), 1);
            LOAD_SLOT(3, tb + 7); WAITP; EXP_SLOT(0);
        }

        // z_c = sum_s P[s][c]*exp(end[s]); states at this lane: 16n+4q+i
        float zacc = 0.f;
#pragma unroll
        for (int i = 0; i < 4; ++i) {
            zacc += pn0[i] * __expf(endT[ 0 + 4 * qidx + i]);
            zacc += pn1[i] * __expf(endT[16 + 4 * qidx + i]);
            zacc += pn2[i] * __expf(endT[32 + 4 * qidx + i]);
        }
        zacc += __shfl_xor(zacc, 16, 64);
        zacc += __shfl_xor(zacc, 32, 64);
        float nl = -(__logf(zacc) + (float)c2 * 0.6931471805599453f);
        nl += __shfl_xor(nl, 1, 64);
        nl += __shfl_xor(nl, 2, 64);
        nl += __shfl_xor(nl, 4, 64);
        nl += __shfl_xor(nl, 8, 64);
        if (j == 0) atomicAdd(out, nl);
        // drain remaining in-flight asm loads before wave exit
        asm volatile("s_waitcnt vmcnt(0)");
    } else {
        // ---------------- numerator path ----------------
        const int bid = blockIdx.x - 64;          // 0..511
        float c = 0.0f;
        for (int id = bid * 64 + j; id < Lq * Bn; id += 512 * 64) {
            int t  = id >> 10;
            int bb = id & (Bn - 1);
            int tag = tags[id];
            int m_t = mask[id];
            if (t == 0) c += startT[tag];
            bool is_last;
            if (t < Lq - 1) {
                if (m_t) c += em[(size_t)id * Tq + tag];
                int tag1 = tags[id + Bn];
                int m1   = mask[id + Bn];
                if (m1) c += trans[tag * Tq + tag1];
                is_last = (m_t != 0) && (m1 == 0);
            } else {
                is_last = (m_t != 0);
            }
            if (is_last) {
                c += endT[tag];
                int mL = mask[(Lq - 1) * Bn + bb];
                if (mL) c += em[((size_t)(Lq - 1) * Bn + bb) * Tq + tag];
            }
        }
#pragma unroll
        for (int off = 32; off >= 1; off >>= 1)
            c += __shfl_xor(c, off, 64);
        if (j == 0) atomicAdd(out, c);
    }
}

extern "C" void kernel_launch(void* const* d_in, const int* in_sizes, int n_in,
                              void* d_out, int out_size, void* d_ws, size_t ws_size,
                              hipStream_t stream) {
    const float* em     = (const float*)d_in[0];
    const int*   tags   = (const int*)d_in[1];
    const int*   mask   = (const int*)d_in[2];
    const float* startT = (const float*)d_in[3];
    const float* endT   = (const float*)d_in[4];
    const float* trans  = (const float*)d_in[5];
    float* out = (float*)d_out;

    hipMemsetAsync(out, 0, sizeof(float), stream);
    crf_fused<<<576, 64, 0, stream>>>(em, tags, mask, startT, endT, trans, out);
}